// Round 9
// baseline (121.601 us; speedup 1.0000x reference)
//
#include <hip/hip_runtime.h>
#include <hip/hip_bf16.h>

#define N_OBJ   32
#define G_TOTAL 4960      // C(32,3)
#define GPAD    5120      // K padded for clean split-K
#define N_FILT  16
#define REL_D   16
#define BATCH   32
#define NQ      512
#define ZSPLIT  4
#define KCH     1280      // GPAD / ZSPLIT
#define NIT     40        // KCH / 32

typedef __attribute__((ext_vector_type(8))) short bf16x8;
typedef __attribute__((ext_vector_type(4))) float f32x4;

static __device__ inline unsigned short f2bf(float x) {
    union { float f; unsigned int u; } v; v.f = x;
    unsigned int r = v.u + 0x7fffu + ((v.u >> 16) & 1u);   // RNE
    return (unsigned short)(r >> 16);
}
static __device__ inline void gload_lds16(const void* g, void* l) {
    __builtin_amdgcn_global_load_lds(
        (const __attribute__((address_space(1))) unsigned int*)g,
        (__attribute__((address_space(3))) unsigned int*)(unsigned int)(uintptr_t)l,
        16, 0, 0);
}
// unrank lexicographic 3-combination of 32
static __device__ inline void unrank3(int g, int& a, int& b, int& c) {
    int rem = g;
    for (a = 0; a < 30; a++) { int cnt = ((31 - a) * (30 - a)) >> 1; if (rem < cnt) break; rem -= cnt; }
    for (b = a + 1; b < 31; b++) { if (rem < 31 - b) break; rem -= 31 - b; }
    c = b + 1 + rem;
}

// ========== Node 1: rel-direct (roles 0..619) + normw (620..1131) + zero-out ======
// rel-direct: thread = (g_local, b); 16 filter accumulators in VGPRs; inputs rows
// gathered from L2 (2 MB, L2-resident) with 36-deep load ILP; filters are
// thread-uniform -> s_load through K$. No LDS, no syncthreads in this role.
__global__ __launch_bounds__(256) void k_front(const float* __restrict__ logits,
                                               const float* __restrict__ inputs,
                                               const float* __restrict__ filters,
                                               unsigned short* __restrict__ normw,
                                               unsigned short* __restrict__ relT,
                                               float* __restrict__ out) {
    __shared__ __align__(16) char smem[10624];
    int t = threadIdx.x;
    int role = blockIdx.x;

    if (role < 620) {
        // ---------- rel[n=b*16+f][g] = sum_ij dot16(inputs[b,xi,xj,:], filters[f,ij,:])
        int gl = t >> 5, b = t & 31;
        int g = role * 8 + gl;                 // < 4960 always
        int xs[3];
        unrank3(g, xs[0], xs[1], xs[2]);

        float acc[16];
#pragma unroll
        for (int f = 0; f < 16; f++) acc[f] = 0.f;

        const float* inb = inputs + b * (N_OBJ * N_OBJ * REL_D);
#pragma unroll
        for (int i = 0; i < 3; i++) {
#pragma unroll
            for (int j = 0; j < 3; j++) {
                const float4* src = (const float4*)(inb + xs[i] * (N_OBJ * REL_D) + xs[j] * REL_D);
                float4 s0 = src[0], s1 = src[1], s2 = src[2], s3 = src[3];
                int pp = i * 3 + j;
#pragma unroll
                for (int f = 0; f < 16; f++) {
                    const float4* flt = (const float4*)(filters + f * (9 * REL_D) + pp * REL_D);
                    float4 f0 = flt[0], f1 = flt[1], f2 = flt[2], f3 = flt[3];
                    float d = s0.x * f0.x + s0.y * f0.y + s0.z * f0.z + s0.w * f0.w;
                    d += s1.x * f1.x + s1.y * f1.y + s1.z * f1.z + s1.w * f1.w;
                    d += s2.x * f2.x + s2.y * f2.y + s2.z * f2.z + s2.w * f2.w;
                    d += s3.x * f3.x + s3.y * f3.y + s3.z * f3.z + s3.w * f3.w;
                    acc[f] += d;
                }
            }
        }
        // scatter bf16 stores: 16 x 2B, write-combined in L2
        unsigned short* base = relT + (size_t)(b * 16) * GPAD + g;
#pragma unroll
        for (int f = 0; f < 16; f++) base[(size_t)f * GPAD] = f2bf(acc[f]);
    } else if (role < 620 + NQ) {
        // ---------- normw: softplus -> triple product -> softmax -> bf16, K-padded --
        float* sp  = (float*)smem;                            // 32 floats
        float* red = (float*)(smem + 128);                    // 4 floats
        unsigned short* wrow = (unsigned short*)(smem + 144); // 5120 u16
        int q = role - 620;
        if (t < N_OBJ) {
            float x = logits[q * N_OBJ + t];
            sp[t] = (x > 15.f) ? x : log1pf(expf(x));
        }
        if (t < GPAD - G_TOTAL) wrow[G_TOTAL + t] = 0;        // zero the K-pad
        __syncthreads();

        int g0 = t * 20;
        int aa, bb, cc;
        unrank3(g0, aa, bb, cc);

        float w[20];
        float lmax = -1e30f;
#pragma unroll
        for (int k = 0; k < 20; k++) {
            float v = -1e30f;
            if (g0 + k < G_TOTAL) v = sp[aa] * sp[bb] * sp[cc];
            w[k] = v;
            lmax = fmaxf(lmax, v);
            cc++;
            if (cc >= 32) { bb++; cc = bb + 1; if (cc >= 32) { aa++; bb = aa + 1; cc = bb + 1; } }
        }
#pragma unroll
        for (int off = 32; off; off >>= 1) lmax = fmaxf(lmax, __shfl_down(lmax, off, 64));
        if ((t & 63) == 0) red[t >> 6] = lmax;
        __syncthreads();
        float wmax = fmaxf(fmaxf(red[0], red[1]), fmaxf(red[2], red[3]));

        float lsum = 0.f;
#pragma unroll
        for (int k = 0; k < 20; k++) {
            float e = (g0 + k < G_TOTAL) ? expf(w[k] - wmax) : 0.f;
            w[k] = e;
            lsum += e;
        }
#pragma unroll
        for (int off = 32; off; off >>= 1) lsum += __shfl_down(lsum, off, 64);
        __syncthreads();
        if ((t & 63) == 0) red[t >> 6] = lsum;
        __syncthreads();
        float inv = 1.f / (red[0] + red[1] + red[2] + red[3]);

#pragma unroll
        for (int k = 0; k < 20; k++)
            if (g0 + k < G_TOTAL) wrow[g0 + k] = f2bf(w[k] * inv);
        __syncthreads();
        uint4* dstrow = (uint4*)(normw + (size_t)q * GPAD);
        const uint4* srow = (const uint4*)wrow;
        for (int i = t; i < 640; i += 256) dstrow[i] = srow[i];
    } else {
        // ---------- zero d_out (roles 1132..1147): 16 blocks x 256 thr x 16 float4
        int idx = (role - (620 + NQ)) * 256 + t;
        float4 z = {0.f, 0.f, 0.f, 0.f};
        float4* o4 = (float4*)out;
#pragma unroll
        for (int j = 0; j < 16; j++) o4[idx + j * 4096] = z;
    }
}

// ========== Node 2: out += A(512xGPAD) x B^T, z=4 split-K, atomic epilogue ========
__global__ __launch_bounds__(256) void k_gemm(const unsigned short* __restrict__ A,
                                              const unsigned short* __restrict__ Bm,
                                              float* __restrict__ out) {
    __shared__ __align__(16) unsigned short As[2][64 * 32];
    __shared__ __align__(16) unsigned short Bs[2][64 * 32];
    int tid = threadIdx.x;
    int q0 = blockIdx.x * 64, n0 = blockIdx.y * 64, z = blockIdx.z;
    int k0 = z * KCH;
    int wave = tid >> 6, lane = tid & 63;
    int wm = wave & 1, wn = wave >> 1;
    int row16 = lane & 15, quad = lane >> 4;

    int srow = tid >> 2;
    int schunk = (tid & 3) ^ ((srow >> 1) & 3);
    const unsigned short* ga = A + (size_t)(q0 + srow) * GPAD + k0 + schunk * 8;
    const unsigned short* gb = Bm + (size_t)(n0 + srow) * GPAD + k0 + schunk * 8;
    char* lA = (char*)&As[0][0] + tid * 16;
    char* lB = (char*)&Bs[0][0] + tid * 16;

    f32x4 acc[2][2] = {};
    int fchunk = (quad ^ ((row16 >> 1) & 3)) * 8;

    gload_lds16(ga, lA);
    gload_lds16(gb, lB);
    for (int it = 0; it < NIT; ++it) {
        __syncthreads();
        if (it + 1 < NIT) {
            int nb = (it + 1) & 1;
            gload_lds16(ga + (it + 1) * 32, lA + nb * 64 * 32 * 2);
            gload_lds16(gb + (it + 1) * 32, lB + nb * 64 * 32 * 2);
        }
        int buf = it & 1;
        bf16x8 afr[2], bfr[2];
#pragma unroll
        for (int mi = 0; mi < 2; mi++)
            afr[mi] = *(const bf16x8*)&As[buf][(wm * 32 + mi * 16 + row16) * 32 + fchunk];
#pragma unroll
        for (int ni = 0; ni < 2; ni++)
            bfr[ni] = *(const bf16x8*)&Bs[buf][(wn * 32 + ni * 16 + row16) * 32 + fchunk];
#pragma unroll
        for (int mi = 0; mi < 2; mi++)
#pragma unroll
            for (int ni = 0; ni < 2; ni++)
                acc[mi][ni] = __builtin_amdgcn_mfma_f32_16x16x32_bf16(
                    afr[mi], bfr[ni], acc[mi][ni], 0, 0, 0);
    }

#pragma unroll
    for (int mi = 0; mi < 2; mi++)
#pragma unroll
        for (int ni = 0; ni < 2; ni++)
#pragma unroll
            for (int r = 0; r < 4; r++) {
                int q = q0 + wm * 32 + mi * 16 + quad * 4 + r;
                int n = n0 + wn * 32 + ni * 16 + row16;
                atomicAdd(out + (size_t)(n >> 4) * (NQ * REL_D) + q * REL_D + (n & 15),
                          acc[mi][ni][r]);
            }
}

extern "C" void kernel_launch(void* const* d_in, const int* in_sizes, int n_in,
                              void* d_out, int out_size, void* d_ws, size_t ws_size,
                              hipStream_t stream) {
    const float* inputs  = (const float*)d_in[0];   // (32,32,32,16)
    const float* logits  = (const float*)d_in[1];   // (512,32)
    const float* filters = (const float*)d_in[2];   // (16,3,3,16)
    float* out = (float*)d_out;                     // (32,512,16)

    char* ws = (char*)d_ws;
    unsigned short* normw = (unsigned short*)ws;                 //  5,242,880 B
    unsigned short* relT  = (unsigned short*)(ws + 5242880);     //  5,242,880 B

    k_front<<<620 + NQ + 16, 256, 0, stream>>>(logits, inputs, filters, normw, relT, out);
    k_gemm<<<dim3(8, 8, ZSPLIT), 256, 0, stream>>>(normw, relT, out);
}